// Round 3
// baseline (1028.953 us; speedup 1.0000x reference)
//
#include <hip/hip_runtime.h>
#include <math.h>

#define BATCH 1024
#define TSEQ  2048
#define DIN   5
#define H     64
#define BT    4      // elems per block; grid 256 = every CU
#define SSTR  144    // halves/elem: [h1 64 | h2 64 | pad 16] -> exact 2-way banks (free)
#define NOUT  128

typedef _Float16 f16x8 __attribute__((ext_vector_type(8)));
typedef float    f32x4 __attribute__((ext_vector_type(4)));

#if __has_builtin(__builtin_amdgcn_rcpf)
__device__ __forceinline__ float rcp_fast(float x) { return __builtin_amdgcn_rcpf(x); }
#else
__device__ __forceinline__ float rcp_fast(float x) { return 1.0f / x; }
#endif

#define LOG2E 1.44269504088896f
#define MFMA16(A, B, C) __builtin_amdgcn_mfma_f32_16x16x32_f16((A), (B), (C), 0, 0, 0)

// exp2-based activations; weights/biases pre-scaled by log2e (sigmoid) or
// 2*log2e (tanh gate) so no per-use multiply.
__device__ __forceinline__ float sigm2(float s) {   // s = log2e * p
    return rcp_fast(1.0f + __builtin_amdgcn_exp2f(-s));
}
__device__ __forceinline__ float tanh2(float s) {   // s = 2*log2e * p
    return fmaf(-2.0f, rcp_fast(__builtin_amdgcn_exp2f(s) + 1.0f), 1.0f);
}

// lgkm-only barrier: ds_write visibility without draining vmcnt, so the
// x prefetch loads stay in flight ACROSS the barrier (counted vmcnt at use).
__device__ __forceinline__ void sync_lgkm() {
    asm volatile("s_waitcnt lgkmcnt(0)" ::: "memory");
    __builtin_amdgcn_s_barrier();
    asm volatile("" ::: "memory");
}

// r8 skeleton (512 thr = 8 waves, layer-split: SIMD s hosts wave s (lay-1)
// + wave s+4 (lay-2); 2 waves/SIMD for cross-wave overlap). R3 changes:
//  - lay-2 accumulation split into TWO 2-deep chains (e = bias + y1-part,
//    f = h2-part; merged e[g][0]+f[g][0]): removes 2 dependent-MFMA
//    latencies from the longest post-barrier chain (R2 showed the wall is
//    chain-latency-bound, not MFMA-issue-bound).
//  - x-projection (VALU) pipelined one step ahead: dxs(t=i+1) computed in
//    the gate phase of iter i, so the post-barrier lay-1 chain is
//    read -> 2 MFMAs -> gates with dxs already in registers.
//  - lgkm-only barrier + setprio kept (neutral but harmless per R2).
__global__ __launch_bounds__(512)
void lstm_mfma(const float* __restrict__ x,
               const float* __restrict__ Wih0, const float* __restrict__ Whh0,
               const float* __restrict__ bih0, const float* __restrict__ bhh0,
               const float* __restrict__ Wih1, const float* __restrict__ Whh1,
               const float* __restrict__ bih1, const float* __restrict__ bhh1,
               const float* __restrict__ Wfc,  const float* __restrict__ bfc,
               float* __restrict__ out)
{
    __shared__ alignas(16) _Float16 S[2][BT * SSTR];   // 2.25 KB state, double-buffered
    __shared__ alignas(16) float    h2f[BT][H];        // 1 KB final h2 for FC

    const int tid  = threadIdx.x;
    const int w    = tid >> 6;         // 0..7
    const int lane = tid & 63;
    const int col  = lane & 15;        // n (h-unit offset); A-row m
    const int q    = lane >> 4;        // quad -> C/D row group; k-slice
    const int ww   = w & 3;            // h-unit tile
    const int lay  = w >> 2;           // 0 = layer-1, 1 = layer-2
    const int hu   = 16 * ww + col;
    const int b0   = blockIdx.x * BT;

    // ---- zero both state buffers ----
    for (int j = tid; j < 2 * BT * SSTR; j += 512)
        ((_Float16*)S)[j] = (_Float16)0.0f;

    const float sgl[4] = {LOG2E, LOG2E, 2.0f * LOG2E, LOG2E};  // i,f,g,o

    // ---- B-fragments for THIS wave's layer (registers, pre-scaled) ----
    // B[k=q*8+j][n=col]; n-tile: gate rows g*64 + hu.
    // lay0: [0]=Whh0 k0-31 [1]=Whh0 k32-63  (+ wx/b1s for the VALU x-proj)
    // lay1: [0]=Wih1 k0-31 [1]=Wih1 k32-63 [2]=Whh1 k0-31 [3]=Whh1 k32-63
    f16x8 Bf[4][4];
    f32x4 bC[4];        // lay-2 bias as MFMA C
    float wx[4][DIN];   // lay-1: Wih0 row (pre-scaled), f32
    float b1s[4];       // lay-1 scalar bias
    #pragma unroll
    for (int g = 0; g < 4; ++g) {
        const int   row = g * 64 + hu;
        const float sg  = sgl[g];
        if (lay) {
            const float* wa = Wih1 + row * H;
            const float* wb = Whh1 + row * H;
            #pragma unroll
            for (int j = 0; j < 8; ++j) {
                const int k = q * 8 + j;
                Bf[g][0][j] = (_Float16)(wa[k]      * sg);
                Bf[g][1][j] = (_Float16)(wa[32 + k] * sg);
                Bf[g][2][j] = (_Float16)(wb[k]      * sg);
                Bf[g][3][j] = (_Float16)(wb[32 + k] * sg);
            }
            const float bb = (bih1[row] + bhh1[row]) * sg;
            bC[g] = f32x4{bb, bb, bb, bb};
        } else {
            const float* wh = Whh0 + row * H;
            #pragma unroll
            for (int j = 0; j < 8; ++j) {
                const int k = q * 8 + j;
                Bf[g][0][j] = (_Float16)(wh[k]      * sg);
                Bf[g][1][j] = (_Float16)(wh[32 + k] * sg);
            }
            #pragma unroll
            for (int j = 0; j < DIN; ++j)
                wx[g][j] = Wih0[row * DIN + j] * sg;
            b1s[g] = (bih0[row] + bhh0[row]) * sg;
        }
    }

    // ---- x pipeline (lay-0): dxs(t) ready at iter t; regs carry x(t+1) ----
    // (dxs feeds MFMA C element 0 = D row 4q = elem q, so x index is q.)
    const float* xq = x + (size_t)(b0 + q) * TSEQ * DIN;
    float x0 = 0.f, x1 = 0.f, x2 = 0.f, x3 = 0.f, x4 = 0.f;
    float dxs[4] = {0.f, 0.f, 0.f, 0.f};
    if (lay == 0) {
        // x(0) -> dxs(0)
        float a0 = xq[0], a1 = xq[1], a2 = xq[2], a3 = xq[3], a4 = xq[4];
        #pragma unroll
        for (int g = 0; g < 4; ++g) {
            float s = fmaf(a0, wx[g][0], b1s[g]);
            s = fmaf(a1, wx[g][1], s);
            s = fmaf(a2, wx[g][2], s);
            s = fmaf(a3, wx[g][3], s);
            dxs[g] = fmaf(a4, wx[g][4], s);
        }
        // x(1) -> regs
        x0 = xq[DIN + 0]; x1 = xq[DIN + 1]; x2 = xq[DIN + 2];
        x3 = xq[DIN + 3]; x4 = xq[DIN + 4];
        xq += 2 * DIN;      // -> t=2
    }

    const int ab  = (col >> 2) * SSTR + q * 8;   // A-frag read base (halves)
    const int wb1 = q * SSTR + hu;               // h1 write slot
    const int wb2 = q * SSTR + 64 + hu;          // h2 write slot
    float cst = 0.0f, h2fin = 0.0f;

    __syncthreads();

    // ============ main loop: iter i = layer-1(t=i) & layer-2(t=i-1) ============
    #pragma unroll 1
    for (int i = 0; i <= TSEQ; ++i) {
        const _Float16* rb   = S[(i + 1) & 1];
        _Float16*       wbuf = S[i & 1];

        if (lay == 0) {
            // fire x(i+2) loads first: in flight across sync_lgkm, consumed
            // in iter i+1's gate phase (~1 full wall of latency budget).
            const bool ld2 = (i + 2 < TSEQ);
            float n0, n1, n2, n3, n4;
            if (ld2) { n0 = xq[0]; n1 = xq[1]; n2 = xq[2]; n3 = xq[3]; n4 = xq[4]; xq += DIN; }

            f16x8 a0 = *(const f16x8*)&rb[ab];        // h1 k 0..31
            f16x8 a1 = *(const f16x8*)&rb[ab + 32];   // h1 k 32..63

            f32x4 d[4];
            __builtin_amdgcn_s_setprio(1);
            #pragma unroll
            for (int g = 0; g < 4; ++g) {             // 2-deep chains, 4-way ILP
                f32x4 c0 = {dxs[g], 0.f, 0.f, 0.f};   // only D row 4q (elem q) is read
                d[g] = MFMA16(a0, Bf[g][0], c0);
                d[g] = MFMA16(a1, Bf[g][1], d[g]);
            }
            __builtin_amdgcn_s_setprio(0);

            if (i < TSEQ) {   // layer-1 G for t=i
                float iv = sigm2(d[0][0]);
                float fv = sigm2(d[1][0]);
                float gv = tanh2(d[2][0]);
                float ov = sigm2(d[3][0]);
                cst = fmaf(fv, cst, iv * gv);
                wbuf[wb1] = (_Float16)(ov * tanh2(2.0f * LOG2E * cst));
            }
            // dxs(i+1) off the critical path (x regs hold x(i+1))
            if (i + 1 < TSEQ) {
                #pragma unroll
                for (int g = 0; g < 4; ++g) {
                    float s = fmaf(x0, wx[g][0], b1s[g]);
                    s = fmaf(x1, wx[g][1], s);
                    s = fmaf(x2, wx[g][2], s);
                    s = fmaf(x3, wx[g][3], s);
                    dxs[g] = fmaf(x4, wx[g][4], s);
                }
            }
            if (ld2) { x0 = n0; x1 = n1; x2 = n2; x3 = n3; x4 = n4; }
        } else {
            f16x8 ay0 = *(const f16x8*)&rb[ab];        // y1(t-1) k 0..31
            f16x8 ay1 = *(const f16x8*)&rb[ab + 32];   // y1(t-1) k 32..63
            f16x8 ah0 = *(const f16x8*)&rb[ab + 64];   // h2(t-2) k 0..31
            f16x8 ah1 = *(const f16x8*)&rb[ab + 96];   // h2(t-2) k 32..63
            f32x4 e[4], f[4];
            const f32x4 z4 = {0.f, 0.f, 0.f, 0.f};
            __builtin_amdgcn_s_setprio(1);
            #pragma unroll
            for (int g = 0; g < 4; ++g) {              // 8 chains, all 2-deep
                e[g] = MFMA16(ay0, Bf[g][0], bC[g]);   // bias + y1 part
                e[g] = MFMA16(ay1, Bf[g][1], e[g]);
                f[g] = MFMA16(ah0, Bf[g][2], z4);      // h2 part
                f[g] = MFMA16(ah1, Bf[g][3], f[g]);
            }
            __builtin_amdgcn_s_setprio(0);
            if (i > 0) {      // layer-2 G for t=i-1 (merge split chains: elem 0 only)
                float p0 = e[0][0] + f[0][0];
                float p1 = e[1][0] + f[1][0];
                float p2 = e[2][0] + f[2][0];
                float p3 = e[3][0] + f[3][0];
                float iv = sigm2(p0);
                float fv = sigm2(p1);
                float gv = tanh2(p2);
                float ov = sigm2(p3);
                cst = fmaf(fv, cst, iv * gv);
                h2fin = ov * tanh2(2.0f * LOG2E * cst);
                wbuf[wb2] = (_Float16)h2fin;
            }
        }
        sync_lgkm();
    }

    // ---------------- epilogue: out = relu(h2(T-1) @ Wfc^T + bfc) ----------------
    if (lay) h2f[q][hu] = h2fin;
    __syncthreads();
    {
        const int e = tid >> 7;            // 0..3
        const int o = tid & (NOUT - 1);    // 0..127
        const float4* wr = (const float4*)(Wfc + o * H);
        const float*  hv = h2f[e];
        float s0 = 0.f, s1 = 0.f, s2 = 0.f, s3 = 0.f;
        #pragma unroll
        for (int k = 0; k < H / 4; ++k) {
            float4 wv = wr[k];
            s0 = fmaf(wv.x, hv[4 * k + 0], s0);
            s1 = fmaf(wv.y, hv[4 * k + 1], s1);
            s2 = fmaf(wv.z, hv[4 * k + 2], s2);
            s3 = fmaf(wv.w, hv[4 * k + 3], s3);
        }
        float acc = bfc[o] + (s0 + s1) + (s2 + s3);
        out[(size_t)(b0 + e) * NOUT + o] = fmaxf(acc, 0.0f);
    }
}

extern "C" void kernel_launch(void* const* d_in, const int* in_sizes, int n_in,
                              void* d_out, int out_size, void* d_ws, size_t ws_size,
                              hipStream_t stream) {
    const float* x    = (const float*)d_in[0];
    const float* Wih0 = (const float*)d_in[1];
    const float* Whh0 = (const float*)d_in[2];
    const float* bih0 = (const float*)d_in[3];
    const float* bhh0 = (const float*)d_in[4];
    const float* Wih1 = (const float*)d_in[5];
    const float* Whh1 = (const float*)d_in[6];
    const float* bih1 = (const float*)d_in[7];
    const float* bhh1 = (const float*)d_in[8];
    const float* Wfc  = (const float*)d_in[9];
    const float* bfc  = (const float*)d_in[10];
    float* out = (float*)d_out;

    lstm_mfma<<<dim3(BATCH / BT), dim3(512), 0, stream>>>(
        x, Wih0, Whh0, bih0, bhh0, Wih1, Whh1, bih1, bhh1, Wfc, bfc, out);
}